// Round 1
// baseline (552.749 us; speedup 1.0000x reference)
//
#include <hip/hip_runtime.h>
#include <hip/hip_bf16.h>

// TtAttention: x(2048,4096) -> QKV proj -> RoPE -> windowed causal GQA attention -> O proj.
// All GEMMs in bf16 MFMA (16x16x32), fp32 accumulate. Threshold 0.124 absolute.

typedef __attribute__((ext_vector_type(8))) short short8;
typedef __attribute__((ext_vector_type(4))) float floatx4;
typedef unsigned short u16;
typedef unsigned int u32;

__device__ __forceinline__ u16 f2bf(float f) {
  u32 u = __builtin_bit_cast(u32, f);
  u32 r = u + 0x7FFFu + ((u >> 16) & 1u);
  return (u16)(r >> 16);
}

#define GLDS16(g, l)                                                     \
  __builtin_amdgcn_global_load_lds(                                      \
      (const __attribute__((address_space(1))) u32*)(g),                 \
      (__attribute__((address_space(3))) u32*)(l), 16, 0, 0)

// ---------------------------------------------------------------- cast ----
__global__ __launch_bounds__(256) void cast_kernel(const float* __restrict__ in,
                                                   u16* __restrict__ out, int n4) {
  int i = blockIdx.x * blockDim.x + threadIdx.x;
  int stride = gridDim.x * blockDim.x;
  for (; i < n4; i += stride) {
    float4 v = ((const float4*)in)[i];
    ushort4 o;
    o.x = f2bf(v.x); o.y = f2bf(v.y); o.z = f2bf(v.z); o.w = f2bf(v.w);
    ((ushort4*)out)[i] = o;
  }
}

// ---------------------------------------------------------------- GEMM ----
// C[m][n] = sum_k A[m][k] * B[n][k]   (both operands K-contiguous, B^T form)
// MODE 1: bf16 store + RoPE + 1/sqrt(128) scale (Q)
// MODE 2: bf16 store + RoPE (K)
// MODE 3: fp32 store (final output)
// MODE 4: bf16 TRANSPOSED store Ct[n][m], ldc_t = M (V -> V^T)
template <int MODE>
__global__ __launch_bounds__(256) void gemm_bt(
    const u16* __restrict__ A, const u16* __restrict__ B, void* __restrict__ C,
    int M, int N, int K, int ldc_t, const float* __restrict__ fcos,
    const float* __restrict__ fsin) {
  __shared__ u16 As[128 * 32];
  __shared__ u16 Bs[128 * 32];
  const int t = threadIdx.x;
  const int l = t & 63;
  const int w = t >> 6;
  const int li = l & 15, g = l >> 4;
  const int m0 = blockIdx.y * 128;
  const int n0 = blockIdx.x * 128;
  const int wm = (w >> 1) * 64, wn = (w & 1) * 64;

  // staging: tile [128 rows][32 cols] bf16 = 64B rows, chunk = 1024B = 16 rows.
  // swizzle: phys 16B-slot = logical slot ^ ((row>>1)&3)  (keeps banks 2-way on reads)
  const int c0 = 2 * w, c1 = 2 * w + 1;
  const int rS0 = c0 * 16 + (l >> 2), rS1 = c1 * 16 + (l >> 2);
  const int sS0 = (l & 3) ^ ((rS0 >> 1) & 3), sS1 = (l & 3) ^ ((rS1 >> 1) & 3);
  const u16* gA0 = A + (size_t)(m0 + rS0) * K + sS0 * 8;
  const u16* gA1 = A + (size_t)(m0 + rS1) * K + sS1 * 8;
  const u16* gB0 = B + (size_t)(n0 + rS0) * K + sS0 * 8;
  const u16* gB1 = B + (size_t)(n0 + rS1) * K + sS1 * 8;
  auto ldsA0 = (__attribute__((address_space(3))) u32*)((char*)As + c0 * 1024);
  auto ldsA1 = (__attribute__((address_space(3))) u32*)((char*)As + c1 * 1024);
  auto ldsB0 = (__attribute__((address_space(3))) u32*)((char*)Bs + c0 * 1024);
  auto ldsB1 = (__attribute__((address_space(3))) u32*)((char*)Bs + c1 * 1024);

  int offA[4], offB[4];
#pragma unroll
  for (int i = 0; i < 4; i++) {
    int r = wm + i * 16 + li;
    offA[i] = r * 64 + ((g ^ ((r >> 1) & 3)) << 4);
    int r2 = wn + i * 16 + li;
    offB[i] = r2 * 64 + ((g ^ ((r2 >> 1) & 3)) << 4);
  }

  floatx4 acc[4][4] = {};

  for (int kt = 0; kt < K; kt += 32) {
    __syncthreads();
    GLDS16(gA0 + kt, ldsA0);
    GLDS16(gA1 + kt, ldsA1);
    GLDS16(gB0 + kt, ldsB0);
    GLDS16(gB1 + kt, ldsB1);
    __syncthreads();
    short8 a[4], b[4];
#pragma unroll
    for (int i = 0; i < 4; i++) a[i] = *(const short8*)((const char*)As + offA[i]);
#pragma unroll
    for (int i = 0; i < 4; i++) b[i] = *(const short8*)((const char*)Bs + offB[i]);
#pragma unroll
    for (int mi = 0; mi < 4; mi++)
#pragma unroll
      for (int ni = 0; ni < 4; ni++)
        acc[mi][ni] = __builtin_amdgcn_mfma_f32_16x16x32_bf16(a[mi], b[ni], acc[mi][ni], 0, 0, 0);
  }

  const float scale = 0.08838834764831845f;  // 128^-0.5
#pragma unroll
  for (int mi = 0; mi < 4; mi++) {
#pragma unroll
    for (int ni = 0; ni < 4; ni++) {
      const int row0 = m0 + wm + mi * 16 + 4 * g;
      const int col = n0 + wn + ni * 16 + li;
      if constexpr (MODE == 3) {
        float* Cf = (float*)C;
#pragma unroll
        for (int r = 0; r < 4; r++) Cf[(size_t)(row0 + r) * N + col] = acc[mi][ni][r];
      } else if constexpr (MODE == 4) {
        u16* Ct = (u16*)C;
        u32 lo = (u32)f2bf(acc[mi][ni][0]) | ((u32)f2bf(acc[mi][ni][1]) << 16);
        u32 hi = (u32)f2bf(acc[mi][ni][2]) | ((u32)f2bf(acc[mi][ni][3]) << 16);
        uint2 val; val.x = lo; val.y = hi;
        *(uint2*)(&Ct[(size_t)col * ldc_t + row0]) = val;
      } else {  // RoPE modes
        u16* Cb = (u16*)C;
        const int hd = col & 127;
        const int p = hd >> 1;
        const bool even = (hd & 1) == 0;
#pragma unroll
        for (int r = 0; r < 4; r++) {
          const int row = row0 + r;
          float cv = fcos[row * 64 + p];
          float sv = fsin[row * 64 + p];
          float v = acc[mi][ni][r];
          float pv = __shfl_xor(v, 1);
          float o = even ? (v * cv - pv * sv) : (pv * sv + v * cv);
          if constexpr (MODE == 1) o *= scale;
          Cb[(size_t)row * N + col] = f2bf(o);
        }
      }
    }
  }
}

// ----------------------------------------------------------- attention ----
// Q (2048,4096) bf16 (RoPE'd, pre-scaled), K (2048,1024) bf16 (RoPE'd),
// Vt (1024,2048) bf16 = V^T. O (2048,4096) bf16.
// grid (S/64, H); 4 waves, wave w owns q rows [q0+16w, q0+16w+16).
__global__ __launch_bounds__(256) void attn_kernel(const u16* __restrict__ Q,
                                                   const u16* __restrict__ K,
                                                   const u16* __restrict__ Vt,
                                                   u16* __restrict__ O) {
  __shared__ u16 Ks[32 * 128];   // [k][d], 256B rows, slot ^= row&7
  __shared__ u16 Vs[128 * 32];   // [d][k], 64B rows, slot ^= (row>>1)&3
  __shared__ u16 Ps[4][16 * 40]; // per-wave P relayout, stride 40 (bank-spread)

  const int t = threadIdx.x, l = t & 63, w = t >> 6;
  const int li = l & 15, g = l >> 4;
  const int q0 = blockIdx.x * 64;
  const int h = blockIdx.y;
  const int kvh = h >> 2;
  const int qw = q0 + w * 16;

  // Q fragments (held in regs across all kv tiles)
  short8 qf[4];
  {
    const u16* qp = Q + (size_t)(qw + li) * 4096 + h * 128 + g * 8;
#pragma unroll
    for (int kk = 0; kk < 4; kk++) qf[kk] = *(const short8*)(qp + kk * 32);
  }

  // staging coords
  const int c0 = 2 * w, c1 = 2 * w + 1;
  // K tile: chunk = 1024B = 4 rows (256B rows, 16 slots)
  const int rK0 = c0 * 4 + (l >> 4), rK1 = c1 * 4 + (l >> 4);
  const int sK0 = (l & 15) ^ (rK0 & 7), sK1 = (l & 15) ^ (rK1 & 7);
  const u16* gK0 = K + (size_t)rK0 * 1024 + kvh * 128 + sK0 * 8;
  const u16* gK1 = K + (size_t)rK1 * 1024 + kvh * 128 + sK1 * 8;
  // V tile: chunk = 16 rows (64B rows, 4 slots)
  const int rV0 = c0 * 16 + (l >> 2), rV1 = c1 * 16 + (l >> 2);
  const int sV0 = (l & 3) ^ ((rV0 >> 1) & 3), sV1 = (l & 3) ^ ((rV1 >> 1) & 3);
  const u16* gV0 = Vt + (size_t)(kvh * 128 + rV0) * 2048 + sV0 * 8;
  const u16* gV1 = Vt + (size_t)(kvh * 128 + rV1) * 2048 + sV1 * 8;
  auto ldsK0 = (__attribute__((address_space(3))) u32*)((char*)Ks + c0 * 1024);
  auto ldsK1 = (__attribute__((address_space(3))) u32*)((char*)Ks + c1 * 1024);
  auto ldsV0 = (__attribute__((address_space(3))) u32*)((char*)Vs + c0 * 1024);
  auto ldsV1 = (__attribute__((address_space(3))) u32*)((char*)Vs + c1 * 1024);

  int offK[2][4];
#pragma unroll
  for (int n = 0; n < 2; n++) {
    int r = 16 * n + li;
#pragma unroll
    for (int kk = 0; kk < 4; kk++)
      offK[n][kk] = r * 256 + (((kk * 4 + g) ^ (r & 7)) << 4);
  }
  int offV[8];
#pragma unroll
  for (int dt = 0; dt < 8; dt++) {
    int r = dt * 16 + li;
    offV[dt] = r * 64 + ((g ^ ((r >> 1) & 3)) << 4);
  }

  float mrow[4] = {-1e30f, -1e30f, -1e30f, -1e30f};
  float lsum[4] = {0.f, 0.f, 0.f, 0.f};
  floatx4 accO[8] = {};

  int klo = q0 - 1023;
  if (klo < 0) klo = 0;
  klo &= ~31;
  const int khi = q0 + 63;

  for (int k0 = klo; k0 <= khi; k0 += 32) {
    __syncthreads();
    GLDS16(gK0 + (size_t)k0 * 1024, ldsK0);
    GLDS16(gK1 + (size_t)k0 * 1024, ldsK1);
    GLDS16(gV0 + k0, ldsV0);
    GLDS16(gV1 + k0, ldsV1);
    __syncthreads();

    if (k0 <= qw + 15 && k0 + 31 >= qw - 1023) {
      floatx4 s[2] = {};
#pragma unroll
      for (int kk = 0; kk < 4; kk++) {
#pragma unroll
        for (int n = 0; n < 2; n++) {
          short8 kf = *(const short8*)((const char*)Ks + offK[n][kk]);
          s[n] = __builtin_amdgcn_mfma_f32_16x16x32_bf16(qf[kk], kf, s[n], 0, 0, 0);
        }
      }
      // windowed causal mask
      const bool full = (k0 + 31 <= qw) && (k0 >= qw + 15 - 1023);
      if (!full) {
#pragma unroll
        for (int n = 0; n < 2; n++) {
          const int kc = k0 + n * 16 + li;
#pragma unroll
          for (int r = 0; r < 4; r++) {
            const int qr = qw + 4 * g + r;
            if (kc > qr || qr - kc > 1023) s[n][r] = -__builtin_inff();
          }
        }
      }
      // row max over 16 lanes of the group
      float rm[4];
#pragma unroll
      for (int r = 0; r < 4; r++) rm[r] = fmaxf(s[0][r], s[1][r]);
#pragma unroll
      for (int msk = 1; msk <= 8; msk <<= 1)
#pragma unroll
        for (int r = 0; r < 4; r++) rm[r] = fmaxf(rm[r], __shfl_xor(rm[r], msk));
      // online-softmax update
      float al[4];
#pragma unroll
      for (int r = 0; r < 4; r++) {
        float mn = fmaxf(mrow[r], rm[r]);
        al[r] = __expf(mrow[r] - mn);
        mrow[r] = mn;
        lsum[r] *= al[r];
      }
#pragma unroll
      for (int dt = 0; dt < 8; dt++)
#pragma unroll
        for (int r = 0; r < 4; r++) accO[dt][r] *= al[r];
      // P = exp(S - m), row sum
      float pvv[2][4];
      float rs[4] = {0.f, 0.f, 0.f, 0.f};
#pragma unroll
      for (int n = 0; n < 2; n++)
#pragma unroll
        for (int r = 0; r < 4; r++) {
          float p = __expf(s[n][r] - mrow[r]);
          pvv[n][r] = p;
          rs[r] += p;
        }
#pragma unroll
      for (int msk = 1; msk <= 8; msk <<= 1)
#pragma unroll
        for (int r = 0; r < 4; r++) rs[r] += __shfl_xor(rs[r], msk);
#pragma unroll
      for (int r = 0; r < 4; r++) lsum[r] += rs[r];
      // P relayout through per-wave LDS (A-frag wants row=li, k contiguous)
      u16* pw = &Ps[w][0];
#pragma unroll
      for (int n = 0; n < 2; n++)
#pragma unroll
        for (int r = 0; r < 4; r++)
          pw[(4 * g + r) * 40 + n * 16 + li] = f2bf(pvv[n][r]);
      short8 pa = *(const short8*)((const char*)&Ps[w][0] + li * 80 + g * 16);
      // PV
#pragma unroll
      for (int dt = 0; dt < 8; dt++) {
        short8 vf = *(const short8*)((const char*)Vs + offV[dt]);
        accO[dt] = __builtin_amdgcn_mfma_f32_16x16x32_bf16(pa, vf, accO[dt], 0, 0, 0);
      }
    }
  }

#pragma unroll
  for (int dt = 0; dt < 8; dt++)
#pragma unroll
    for (int r = 0; r < 4; r++) {
      float o = accO[dt][r] / lsum[r];
      O[(size_t)(qw + 4 * g + r) * 4096 + h * 128 + dt * 16 + li] = f2bf(o);
    }
}

// -------------------------------------------------------------- launch ----
extern "C" void kernel_launch(void* const* d_in, const int* in_sizes, int n_in,
                              void* d_out, int out_size, void* d_ws, size_t ws_size,
                              hipStream_t stream) {
  const float* x    = (const float*)d_in[0];
  const float* wq   = (const float*)d_in[1];
  const float* wk   = (const float*)d_in[2];
  const float* wv   = (const float*)d_in[3];
  const float* wo   = (const float*)d_in[4];
  const float* fcos = (const float*)d_in[5];
  const float* fsin = (const float*)d_in[6];
  // d_in[7] mask, d_in[8] positions: unused (window implemented analytically)

  u16* ws  = (u16*)d_ws;
  u16* xb  = ws;               // 2048x4096
  u16* wqb = xb + 8388608;     // 4096x4096
  u16* wkb = wqb + 16777216;   // 1024x4096
  u16* wvb = wkb + 4194304;    // 1024x4096
  u16* wob = wvb + 4194304;    // 4096x4096
  u16* Qb  = wob + 16777216;   // 2048x4096
  u16* Kb  = Qb + 8388608;     // 2048x1024
  u16* Vtb = Kb + 2097152;     // 1024x2048 (V^T)
  u16* AOb = Vtb + 2097152;    // 2048x4096
  // total 71303168 u16 = 142.6 MB workspace

  cast_kernel<<<1024, 256, 0, stream>>>(x, xb, 8388608 / 4);
  cast_kernel<<<1024, 256, 0, stream>>>(wq, wqb, 16777216 / 4);
  cast_kernel<<<512, 256, 0, stream>>>(wk, wkb, 4194304 / 4);
  cast_kernel<<<512, 256, 0, stream>>>(wv, wvb, 4194304 / 4);
  cast_kernel<<<1024, 256, 0, stream>>>(wo, wob, 16777216 / 4);

  gemm_bt<1><<<dim3(32, 16), 256, 0, stream>>>(xb, wqb, Qb, 2048, 4096, 4096, 0, fcos, fsin);
  gemm_bt<2><<<dim3(8, 16), 256, 0, stream>>>(xb, wkb, Kb, 2048, 1024, 4096, 0, fcos, fsin);
  gemm_bt<4><<<dim3(8, 16), 256, 0, stream>>>(xb, wvb, Vtb, 2048, 1024, 4096, 2048, nullptr, nullptr);
  attn_kernel<<<dim3(32, 32), 256, 0, stream>>>(Qb, Kb, Vtb, AOb);
  gemm_bt<3><<<dim3(32, 16), 256, 0, stream>>>(AOb, wob, (float*)d_out, 2048, 4096, 4096, 0, nullptr, nullptr);
}

// Round 2
// 417.099 us; speedup vs baseline: 1.3252x; 1.3252x over previous
//
#include <hip/hip_runtime.h>
#include <hip/hip_bf16.h>

// TtAttention: x(2048,4096) -> QKV proj -> RoPE -> windowed causal GQA attention -> O proj.
// All GEMMs in bf16 MFMA (16x16x32), fp32 accumulate. Threshold 0.124 absolute.

typedef __attribute__((ext_vector_type(8))) short short8;
typedef __attribute__((ext_vector_type(4))) float floatx4;
typedef unsigned short u16;
typedef unsigned int u32;

__device__ __forceinline__ u16 f2bf(float f) {
  u32 u = __builtin_bit_cast(u32, f);
  u32 r = u + 0x7FFFu + ((u >> 16) & 1u);
  return (u16)(r >> 16);
}

#define GLDS16(g, l)                                                     \
  __builtin_amdgcn_global_load_lds(                                      \
      (const __attribute__((address_space(1))) u32*)(g),                 \
      (__attribute__((address_space(3))) u32*)(l), 16, 0, 0)

// ---------------------------------------------------------------- cast ----
// One fused kernel for all 5 fp32->bf16 casts (fewer launch tails).
__global__ __launch_bounds__(256) void cast_all(
    const float* __restrict__ x, const float* __restrict__ wq,
    const float* __restrict__ wk, const float* __restrict__ wv,
    const float* __restrict__ wo, u16* __restrict__ xb, u16* __restrict__ wqb,
    u16* __restrict__ wkb, u16* __restrict__ wvb, u16* __restrict__ wob) {
  const int tid = blockIdx.x * blockDim.x + threadIdx.x;
  const int stride = gridDim.x * blockDim.x;
  auto seg = [&](const float* __restrict__ in, u16* __restrict__ out, int n4) {
    for (int i = tid; i < n4; i += stride) {
      float4 v = ((const float4*)in)[i];
      ushort4 o;
      o.x = f2bf(v.x); o.y = f2bf(v.y); o.z = f2bf(v.z); o.w = f2bf(v.w);
      ((ushort4*)out)[i] = o;
    }
  };
  seg(x, xb, 2097152);
  seg(wq, wqb, 4194304);
  seg(wk, wkb, 1048576);
  seg(wv, wvb, 1048576);
  seg(wo, wob, 4194304);
}

// ---------------------------------------------------------------- GEMM ----
// C[m][n] = sum_k A[m][k] * B[n][k]   (both operands K-contiguous, B^T form)
// MODE 1: bf16 store + RoPE + 1/sqrt(128) scale (Q)
// MODE 3: fp32 store (final output)
template <int MODE>
__global__ __launch_bounds__(256) void gemm_bt(
    const u16* __restrict__ A, const u16* __restrict__ B, void* __restrict__ C,
    int M, int N, int K, int ldc_t, const float* __restrict__ fcos,
    const float* __restrict__ fsin) {
  __shared__ u16 As[128 * 32];
  __shared__ u16 Bs[128 * 32];
  const int t = threadIdx.x;
  const int l = t & 63;
  const int w = t >> 6;
  const int li = l & 15, g = l >> 4;
  const int m0 = blockIdx.y * 128;
  const int n0 = blockIdx.x * 128;
  const int wm = (w >> 1) * 64, wn = (w & 1) * 64;

  const int c0 = 2 * w, c1 = 2 * w + 1;
  const int rS0 = c0 * 16 + (l >> 2), rS1 = c1 * 16 + (l >> 2);
  const int sS0 = (l & 3) ^ ((rS0 >> 1) & 3), sS1 = (l & 3) ^ ((rS1 >> 1) & 3);
  const u16* gA0 = A + (size_t)(m0 + rS0) * K + sS0 * 8;
  const u16* gA1 = A + (size_t)(m0 + rS1) * K + sS1 * 8;
  const u16* gB0 = B + (size_t)(n0 + rS0) * K + sS0 * 8;
  const u16* gB1 = B + (size_t)(n0 + rS1) * K + sS1 * 8;
  auto ldsA0 = (__attribute__((address_space(3))) u32*)((char*)As + c0 * 1024);
  auto ldsA1 = (__attribute__((address_space(3))) u32*)((char*)As + c1 * 1024);
  auto ldsB0 = (__attribute__((address_space(3))) u32*)((char*)Bs + c0 * 1024);
  auto ldsB1 = (__attribute__((address_space(3))) u32*)((char*)Bs + c1 * 1024);

  int offA[4], offB[4];
#pragma unroll
  for (int i = 0; i < 4; i++) {
    int r = wm + i * 16 + li;
    offA[i] = r * 64 + ((g ^ ((r >> 1) & 3)) << 4);
    int r2 = wn + i * 16 + li;
    offB[i] = r2 * 64 + ((g ^ ((r2 >> 1) & 3)) << 4);
  }

  floatx4 acc[4][4] = {};

  for (int kt = 0; kt < K; kt += 32) {
    __syncthreads();
    GLDS16(gA0 + kt, ldsA0);
    GLDS16(gA1 + kt, ldsA1);
    GLDS16(gB0 + kt, ldsB0);
    GLDS16(gB1 + kt, ldsB1);
    __syncthreads();
    short8 a[4], b[4];
#pragma unroll
    for (int i = 0; i < 4; i++) a[i] = *(const short8*)((const char*)As + offA[i]);
#pragma unroll
    for (int i = 0; i < 4; i++) b[i] = *(const short8*)((const char*)Bs + offB[i]);
#pragma unroll
    for (int mi = 0; mi < 4; mi++)
#pragma unroll
      for (int ni = 0; ni < 4; ni++)
        acc[mi][ni] = __builtin_amdgcn_mfma_f32_16x16x32_bf16(a[mi], b[ni], acc[mi][ni], 0, 0, 0);
  }

  const float scale = 0.08838834764831845f;  // 128^-0.5
#pragma unroll
  for (int mi = 0; mi < 4; mi++) {
#pragma unroll
    for (int ni = 0; ni < 4; ni++) {
      const int row0 = m0 + wm + mi * 16 + 4 * g;
      const int col = n0 + wn + ni * 16 + li;
      if constexpr (MODE == 3) {
        float* Cf = (float*)C;
#pragma unroll
        for (int r = 0; r < 4; r++) Cf[(size_t)(row0 + r) * N + col] = acc[mi][ni][r];
      } else {  // RoPE + scale (Q)
        u16* Cb = (u16*)C;
        const int hd = col & 127;
        const int p = hd >> 1;
        const bool even = (hd & 1) == 0;
#pragma unroll
        for (int r = 0; r < 4; r++) {
          const int row = row0 + r;
          float cv = fcos[row * 64 + p];
          float sv = fsin[row * 64 + p];
          float v = acc[mi][ni][r];
          float pv = __shfl_xor(v, 1);
          float o = even ? (v * cv - pv * sv) : (pv * sv + v * cv);
          if constexpr (MODE == 1) o *= scale;
          Cb[(size_t)row * N + col] = f2bf(o);
        }
      }
    }
  }
}

// Fused K+V projection: grid (16,16). blocks x<8 -> K (RoPE store, N=1024),
// x>=8 -> V (transposed bf16 store to V^T, ldc 2048). Fills all 256 CUs.
__global__ __launch_bounds__(256) void gemm_kv(
    const u16* __restrict__ A, const u16* __restrict__ Bk,
    const u16* __restrict__ Bv, u16* __restrict__ Kb, u16* __restrict__ Vtb,
    const float* __restrict__ fcos, const float* __restrict__ fsin) {
  __shared__ u16 As[128 * 32];
  __shared__ u16 Bs[128 * 32];
  const int t = threadIdx.x;
  const int l = t & 63;
  const int w = t >> 6;
  const int li = l & 15, g = l >> 4;
  const int m0 = blockIdx.y * 128;
  const bool isK = blockIdx.x < 8;
  const u16* B = isK ? Bk : Bv;
  const int n0 = (isK ? blockIdx.x : blockIdx.x - 8) * 128;
  const int wm = (w >> 1) * 64, wn = (w & 1) * 64;

  const int c0 = 2 * w, c1 = 2 * w + 1;
  const int rS0 = c0 * 16 + (l >> 2), rS1 = c1 * 16 + (l >> 2);
  const int sS0 = (l & 3) ^ ((rS0 >> 1) & 3), sS1 = (l & 3) ^ ((rS1 >> 1) & 3);
  const u16* gA0 = A + (size_t)(m0 + rS0) * 4096 + sS0 * 8;
  const u16* gA1 = A + (size_t)(m0 + rS1) * 4096 + sS1 * 8;
  const u16* gB0 = B + (size_t)(n0 + rS0) * 4096 + sS0 * 8;
  const u16* gB1 = B + (size_t)(n0 + rS1) * 4096 + sS1 * 8;
  auto ldsA0 = (__attribute__((address_space(3))) u32*)((char*)As + c0 * 1024);
  auto ldsA1 = (__attribute__((address_space(3))) u32*)((char*)As + c1 * 1024);
  auto ldsB0 = (__attribute__((address_space(3))) u32*)((char*)Bs + c0 * 1024);
  auto ldsB1 = (__attribute__((address_space(3))) u32*)((char*)Bs + c1 * 1024);

  int offA[4], offB[4];
#pragma unroll
  for (int i = 0; i < 4; i++) {
    int r = wm + i * 16 + li;
    offA[i] = r * 64 + ((g ^ ((r >> 1) & 3)) << 4);
    int r2 = wn + i * 16 + li;
    offB[i] = r2 * 64 + ((g ^ ((r2 >> 1) & 3)) << 4);
  }

  floatx4 acc[4][4] = {};

  for (int kt = 0; kt < 4096; kt += 32) {
    __syncthreads();
    GLDS16(gA0 + kt, ldsA0);
    GLDS16(gA1 + kt, ldsA1);
    GLDS16(gB0 + kt, ldsB0);
    GLDS16(gB1 + kt, ldsB1);
    __syncthreads();
    short8 a[4], b[4];
#pragma unroll
    for (int i = 0; i < 4; i++) a[i] = *(const short8*)((const char*)As + offA[i]);
#pragma unroll
    for (int i = 0; i < 4; i++) b[i] = *(const short8*)((const char*)Bs + offB[i]);
#pragma unroll
    for (int mi = 0; mi < 4; mi++)
#pragma unroll
      for (int ni = 0; ni < 4; ni++)
        acc[mi][ni] = __builtin_amdgcn_mfma_f32_16x16x32_bf16(a[mi], b[ni], acc[mi][ni], 0, 0, 0);
  }

#pragma unroll
  for (int mi = 0; mi < 4; mi++) {
#pragma unroll
    for (int ni = 0; ni < 4; ni++) {
      const int row0 = m0 + wm + mi * 16 + 4 * g;
      const int col = n0 + wn + ni * 16 + li;
      if (isK) {
        const int hd = col & 127;
        const int p = hd >> 1;
        const bool even = (hd & 1) == 0;
#pragma unroll
        for (int r = 0; r < 4; r++) {
          const int row = row0 + r;
          float cv = fcos[row * 64 + p];
          float sv = fsin[row * 64 + p];
          float v = acc[mi][ni][r];
          float pvx = __shfl_xor(v, 1);
          float o = even ? (v * cv - pvx * sv) : (pvx * sv + v * cv);
          Kb[(size_t)row * 1024 + col] = f2bf(o);
        }
      } else {
        u32 lo = (u32)f2bf(acc[mi][ni][0]) | ((u32)f2bf(acc[mi][ni][1]) << 16);
        u32 hi = (u32)f2bf(acc[mi][ni][2]) | ((u32)f2bf(acc[mi][ni][3]) << 16);
        uint2 val; val.x = lo; val.y = hi;
        *(uint2*)(&Vtb[(size_t)col * 2048 + row0]) = val;
      }
    }
  }
}

// ----------------------------------------------------------- attention ----
// Q (2048,4096) bf16 (RoPE'd, pre-scaled), K (2048,1024) bf16 (RoPE'd),
// Vt (1024,2048) bf16 = V^T. O (2048,4096) bf16.
// grid (S/64, H); 4 waves, wave w owns q rows [q0+16w, q0+16w+16).
// KVBLK=64, double-buffered K/V LDS, T3-minimum 2-phase schedule:
//   STAGE(next buf) -> compute(cur buf) -> vmcnt(0) -> s_barrier (one/tile).
__global__ __launch_bounds__(256) void attn_kernel(const u16* __restrict__ Q,
                                                   const u16* __restrict__ K,
                                                   const u16* __restrict__ Vt,
                                                   u16* __restrict__ O) {
  __shared__ u16 Ks[2][64 * 128];   // [k][d], 256B rows, slot ^= row&7
  __shared__ u16 Vs[2][128 * 64];   // [d][k], 128B rows, slot ^= row&7
  __shared__ u16 Ps[4][16 * 72];    // per-wave P relayout, stride 72

  const int t = threadIdx.x, l = t & 63, w = t >> 6;
  const int li = l & 15, g = l >> 4;
  const int q0 = blockIdx.x * 64;
  const int h = blockIdx.y;
  const int kvh = h >> 2;
  const int qw = q0 + w * 16;

  // Q fragments (held in regs across all kv tiles)
  short8 qf[4];
  {
    const u16* qp = Q + (size_t)(qw + li) * 4096 + h * 128 + g * 8;
#pragma unroll
    for (int kk = 0; kk < 4; kk++) qf[kk] = *(const short8*)(qp + kk * 32);
  }

  // staging: per-wave 4 chunks of 1KB for K tile (16KB) and V tile (16KB)
  const u16* gK[4];
  const u16* gV[4];
  int ldsOff[4];
#pragma unroll
  for (int i = 0; i < 4; i++) {
    int rK = 16 * w + 4 * i + (l >> 4);            // K tile row (256B rows)
    int sK = (l & 15) ^ (rK & 7);
    gK[i] = K + (size_t)rK * 1024 + kvh * 128 + sK * 8;
    int rV = 32 * w + 8 * i + (l >> 3);            // V^T tile row (128B rows)
    int sV = (l & 7) ^ (rV & 7);
    gV[i] = Vt + (size_t)(kvh * 128 + rV) * 2048 + sV * 8;
    ldsOff[i] = (4 * w + i) * 1024;
  }

  int offK[4][4];
#pragma unroll
  for (int n = 0; n < 4; n++) {
    int r = 16 * n + li;
#pragma unroll
    for (int kk = 0; kk < 4; kk++)
      offK[n][kk] = r * 256 + (((kk * 4 + g) ^ (r & 7)) << 4);
  }
  int offV[2][8];
#pragma unroll
  for (int kb = 0; kb < 2; kb++)
#pragma unroll
    for (int dt = 0; dt < 8; dt++) {
      int d = dt * 16 + li;
      offV[kb][dt] = d * 128 + (((kb * 4 + g) ^ (d & 7)) << 4);
    }

  float mrow[4] = {-1e30f, -1e30f, -1e30f, -1e30f};
  float lsum[4] = {0.f, 0.f, 0.f, 0.f};
  floatx4 accO[8] = {};

  int klo = q0 - 1023;
  if (klo < 0) klo = 0;
  klo &= ~63;
  const int nt = (q0 + 64 - klo) >> 6;

  auto stage = [&](int buf, int k0) {
    char* ksb = (char*)&Ks[buf][0];
    char* vsb = (char*)&Vs[buf][0];
#pragma unroll
    for (int i = 0; i < 4; i++) GLDS16(gK[i] + (size_t)k0 * 1024, ksb + ldsOff[i]);
#pragma unroll
    for (int i = 0; i < 4; i++) GLDS16(gV[i] + k0, vsb + ldsOff[i]);
  };

  stage(0, klo);
  asm volatile("s_waitcnt vmcnt(0)" ::: "memory");
  __builtin_amdgcn_s_barrier();

  for (int it = 0; it < nt; it++) {
    const int k0 = klo + (it << 6);
    if (it + 1 < nt) stage((it + 1) & 1, k0 + 64);

    if (k0 <= qw + 15 && k0 + 63 >= qw - 1023) {
      const char* kb = (const char*)&Ks[it & 1][0];
      const char* vb = (const char*)&Vs[it & 1][0];
      floatx4 s[4] = {};
      __builtin_amdgcn_s_setprio(1);
#pragma unroll
      for (int kk = 0; kk < 4; kk++)
#pragma unroll
        for (int n = 0; n < 4; n++) {
          short8 kf = *(const short8*)(kb + offK[n][kk]);
          s[n] = __builtin_amdgcn_mfma_f32_16x16x32_bf16(qf[kk], kf, s[n], 0, 0, 0);
        }
      __builtin_amdgcn_s_setprio(0);
      // windowed causal mask
      const bool full = (k0 + 63 <= qw) && (k0 >= qw + 15 - 1023);
      if (!full) {
#pragma unroll
        for (int n = 0; n < 4; n++) {
          const int kc = k0 + n * 16 + li;
#pragma unroll
          for (int r = 0; r < 4; r++) {
            const int qr = qw + 4 * g + r;
            if (kc > qr || qr - kc > 1023) s[n][r] = -__builtin_inff();
          }
        }
      }
      // row max (over 4 n-tiles in-lane, then 16 lanes)
      float rm[4];
#pragma unroll
      for (int r = 0; r < 4; r++)
        rm[r] = fmaxf(fmaxf(s[0][r], s[1][r]), fmaxf(s[2][r], s[3][r]));
#pragma unroll
      for (int msk = 1; msk <= 8; msk <<= 1)
#pragma unroll
        for (int r = 0; r < 4; r++) rm[r] = fmaxf(rm[r], __shfl_xor(rm[r], msk));
      // online-softmax update
      float al[4];
#pragma unroll
      for (int r = 0; r < 4; r++) {
        float mn = fmaxf(mrow[r], rm[r]);
        al[r] = __expf(mrow[r] - mn);
        mrow[r] = mn;
        lsum[r] *= al[r];
      }
#pragma unroll
      for (int dt = 0; dt < 8; dt++)
#pragma unroll
        for (int r = 0; r < 4; r++) accO[dt][r] *= al[r];
      // P = exp(S - m), row sums, relayout via per-wave LDS
      float rs[4] = {0.f, 0.f, 0.f, 0.f};
      u16* pw = &Ps[w][0];
#pragma unroll
      for (int n = 0; n < 4; n++)
#pragma unroll
        for (int r = 0; r < 4; r++) {
          float p = __expf(s[n][r] - mrow[r]);
          rs[r] += p;
          pw[(4 * g + r) * 72 + n * 16 + li] = f2bf(p);
        }
#pragma unroll
      for (int msk = 1; msk <= 8; msk <<= 1)
#pragma unroll
        for (int r = 0; r < 4; r++) rs[r] += __shfl_xor(rs[r], msk);
#pragma unroll
      for (int r = 0; r < 4; r++) lsum[r] += rs[r];
      short8 pa[2];
#pragma unroll
      for (int kbi = 0; kbi < 2; kbi++)
        pa[kbi] = *(const short8*)((const char*)&Ps[w][0] + li * 144 + kbi * 64 + g * 16);
      // PV
      __builtin_amdgcn_s_setprio(1);
#pragma unroll
      for (int kbi = 0; kbi < 2; kbi++)
#pragma unroll
        for (int dt = 0; dt < 8; dt++) {
          short8 vf = *(const short8*)(vb + offV[kbi][dt]);
          accO[dt] = __builtin_amdgcn_mfma_f32_16x16x32_bf16(pa[kbi], vf, accO[dt], 0, 0, 0);
        }
      __builtin_amdgcn_s_setprio(0);
    }
    asm volatile("s_waitcnt vmcnt(0)" ::: "memory");
    __builtin_amdgcn_s_barrier();
  }

  float inv[4];
#pragma unroll
  for (int r = 0; r < 4; r++) inv[r] = 1.0f / lsum[r];
#pragma unroll
  for (int dt = 0; dt < 8; dt++)
#pragma unroll
    for (int r = 0; r < 4; r++)
      O[(size_t)(qw + 4 * g + r) * 4096 + h * 128 + dt * 16 + li] =
          f2bf(accO[dt][r] * inv[r]);
}

// -------------------------------------------------------------- launch ----
extern "C" void kernel_launch(void* const* d_in, const int* in_sizes, int n_in,
                              void* d_out, int out_size, void* d_ws, size_t ws_size,
                              hipStream_t stream) {
  const float* x    = (const float*)d_in[0];
  const float* wq   = (const float*)d_in[1];
  const float* wk   = (const float*)d_in[2];
  const float* wv   = (const float*)d_in[3];
  const float* wo   = (const float*)d_in[4];
  const float* fcos = (const float*)d_in[5];
  const float* fsin = (const float*)d_in[6];
  // d_in[7] mask, d_in[8] positions: unused (window implemented analytically)

  u16* ws  = (u16*)d_ws;
  u16* xb  = ws;               // 2048x4096
  u16* wqb = xb + 8388608;     // 4096x4096
  u16* wkb = wqb + 16777216;   // 1024x4096
  u16* wvb = wkb + 4194304;    // 1024x4096
  u16* wob = wvb + 4194304;    // 4096x4096
  u16* Qb  = wob + 16777216;   // 2048x4096
  u16* Kb  = Qb + 8388608;     // 2048x1024
  u16* Vtb = Kb + 2097152;     // 1024x2048 (V^T)
  u16* AOb = Vtb + 2097152;    // 2048x4096

  cast_all<<<2048, 256, 0, stream>>>(x, wq, wk, wv, wo, xb, wqb, wkb, wvb, wob);
  gemm_bt<1><<<dim3(32, 16), 256, 0, stream>>>(xb, wqb, Qb, 2048, 4096, 4096, 0, fcos, fsin);
  gemm_kv<<<dim3(16, 16), 256, 0, stream>>>(xb, wkb, wvb, Kb, Vtb, fcos, fsin);
  attn_kernel<<<dim3(32, 32), 256, 0, stream>>>(Qb, Kb, Vtb, AOb);
  gemm_bt<3><<<dim3(32, 16), 256, 0, stream>>>(AOb, wob, (float*)d_out, 2048, 4096, 4096, 0, nullptr, nullptr);
}

// Round 3
// 360.692 us; speedup vs baseline: 1.5325x; 1.1564x over previous
//
#include <hip/hip_runtime.h>
#include <hip/hip_bf16.h>

// TtAttention: x(2048,4096) -> QKV proj -> RoPE -> windowed causal GQA attention -> O proj.
// All GEMMs in bf16 MFMA (16x16x32), fp32 accumulate. Threshold 0.124 absolute.

typedef __attribute__((ext_vector_type(8))) short short8;
typedef __attribute__((ext_vector_type(4))) float floatx4;
typedef unsigned short u16;
typedef unsigned int u32;

__device__ __forceinline__ u16 f2bf(float f) {
  u32 u = __builtin_bit_cast(u32, f);
  u32 r = u + 0x7FFFu + ((u >> 16) & 1u);
  return (u16)(r >> 16);
}

#define GLDS16(g, l)                                                     \
  __builtin_amdgcn_global_load_lds(                                      \
      (const __attribute__((address_space(1))) u32*)(g),                 \
      (__attribute__((address_space(3))) u32*)(l), 16, 0, 0)

// ---------------------------------------------------------------- cast ----
__global__ __launch_bounds__(256) void cast_all(
    const float* __restrict__ x, const float* __restrict__ wq,
    const float* __restrict__ wk, const float* __restrict__ wv,
    const float* __restrict__ wo, u16* __restrict__ xb, u16* __restrict__ wqb,
    u16* __restrict__ wkb, u16* __restrict__ wvb, u16* __restrict__ wob) {
  const int tid = blockIdx.x * blockDim.x + threadIdx.x;
  const int stride = gridDim.x * blockDim.x;
  auto seg = [&](const float* __restrict__ in, u16* __restrict__ out, int n4) {
    for (int i = tid; i < n4; i += stride) {
      float4 v = ((const float4*)in)[i];
      ushort4 o;
      o.x = f2bf(v.x); o.y = f2bf(v.y); o.z = f2bf(v.z); o.w = f2bf(v.w);
      ((ushort4*)out)[i] = o;
    }
  };
  seg(x, xb, 2097152);
  seg(wq, wqb, 4194304);
  seg(wk, wkb, 1048576);
  seg(wv, wvb, 1048576);
  seg(wo, wob, 4194304);
}

// ---------------------------------------------------------------- GEMM ----
// Triple-buffered, counted-vmcnt pipeline (T4): one barrier per K-step,
// vmcnt(4) mid-loop (next tile's 4 loads stay in flight across the barrier).
// IS_QKV=1: A=x, N=6144 = [Q 4096 | K 1024 | V 1024], per-region epilogue.
// IS_QKV=0: A=attn out, B=wo, fp32 store, N=4096.
template <int IS_QKV>
__global__ __launch_bounds__(256) void gemm_pipe(
    const u16* __restrict__ A, const u16* __restrict__ Bq,
    const u16* __restrict__ Bk, const u16* __restrict__ Bv,
    void* __restrict__ Cq, u16* __restrict__ Ck, u16* __restrict__ Cv,
    const float* __restrict__ fcos, const float* __restrict__ fsin) {
  __shared__ u16 As[3][128 * 32];
  __shared__ u16 Bs[3][128 * 32];
  const int K = 4096;
  const int t = threadIdx.x;
  const int l = t & 63;
  const int w = t >> 6;
  const int li = l & 15, g = l >> 4;
  const int m0 = blockIdx.y * 128;
  const int bx = blockIdx.x;
  const int wm = (w >> 1) * 64, wn = (w & 1) * 64;

  // region select (block-uniform)
  const u16* Bbase;
  int n0;  // column offset within the region's weight matrix
  if constexpr (IS_QKV) {
    if (bx < 32) { Bbase = Bq; n0 = bx * 128; }
    else if (bx < 40) { Bbase = Bk; n0 = (bx - 32) * 128; }
    else { Bbase = Bv; n0 = (bx - 40) * 128; }
  } else {
    Bbase = Bq; n0 = bx * 128;
  }

  // staging: tile [128 rows][32 cols] bf16 = 64B rows, chunk = 1024B = 16 rows.
  // swizzle: phys 16B-slot = logical slot ^ ((row>>1)&3)
  const int c0 = 2 * w, c1 = 2 * w + 1;
  const int rS0 = c0 * 16 + (l >> 2), rS1 = c1 * 16 + (l >> 2);
  const int sS0 = (l & 3) ^ ((rS0 >> 1) & 3), sS1 = (l & 3) ^ ((rS1 >> 1) & 3);
  const u16* gA0 = A + (size_t)(m0 + rS0) * K + sS0 * 8;
  const u16* gA1 = A + (size_t)(m0 + rS1) * K + sS1 * 8;
  const u16* gB0 = Bbase + (size_t)(n0 + rS0) * K + sS0 * 8;
  const u16* gB1 = Bbase + (size_t)(n0 + rS1) * K + sS1 * 8;
  const int lo0 = c0 * 1024, lo1 = c1 * 1024;

  int offA[4], offB[4];
#pragma unroll
  for (int i = 0; i < 4; i++) {
    int r = wm + i * 16 + li;
    offA[i] = r * 64 + ((g ^ ((r >> 1) & 3)) << 4);
    int r2 = wn + i * 16 + li;
    offB[i] = r2 * 64 + ((g ^ ((r2 >> 1) & 3)) << 4);
  }

  floatx4 acc[4][4] = {};

  auto stage = [&](int buf, int kt) {
    char* ab = (char*)As + buf * 8192;
    char* bb = (char*)Bs + buf * 8192;
    GLDS16(gA0 + kt, ab + lo0);
    GLDS16(gA1 + kt, ab + lo1);
    GLDS16(gB0 + kt, bb + lo0);
    GLDS16(gB1 + kt, bb + lo1);
  };

  const int NT = K / 32;  // 128
  stage(0, 0);
  int cur = 0, nxt = 1;
  for (int it = 0; it < NT; ++it) {
    if (it + 1 < NT) {
      stage(nxt, (it + 1) * 32);
      asm volatile("s_waitcnt vmcnt(4)" ::: "memory");
    } else {
      asm volatile("s_waitcnt vmcnt(0)" ::: "memory");
    }
    __builtin_amdgcn_s_barrier();
    const char* as = (const char*)As + cur * 8192;
    const char* bs = (const char*)Bs + cur * 8192;
    short8 a[4], b[4];
#pragma unroll
    for (int i = 0; i < 4; i++) a[i] = *(const short8*)(as + offA[i]);
#pragma unroll
    for (int i = 0; i < 4; i++) b[i] = *(const short8*)(bs + offB[i]);
    __builtin_amdgcn_s_setprio(1);
#pragma unroll
    for (int mi = 0; mi < 4; mi++)
#pragma unroll
      for (int ni = 0; ni < 4; ni++)
        acc[mi][ni] = __builtin_amdgcn_mfma_f32_16x16x32_bf16(a[mi], b[ni], acc[mi][ni], 0, 0, 0);
    __builtin_amdgcn_s_setprio(0);
    cur = nxt;
    nxt = (nxt == 2) ? 0 : nxt + 1;
  }

  const float scale = 0.08838834764831845f;  // 128^-0.5
#pragma unroll
  for (int mi = 0; mi < 4; mi++) {
#pragma unroll
    for (int ni = 0; ni < 4; ni++) {
      const int row0 = m0 + wm + mi * 16 + 4 * g;
      const int col = n0 + wn + ni * 16 + li;
      if constexpr (!IS_QKV) {
        float* Cf = (float*)Cq;
#pragma unroll
        for (int r = 0; r < 4; r++) Cf[(size_t)(row0 + r) * 4096 + col] = acc[mi][ni][r];
      } else {
        if (bx < 40) {  // Q or K: RoPE (+scale for Q)
          const int hd = col & 127;
          const int p = hd >> 1;
          const bool even = (hd & 1) == 0;
          const bool isQ = (bx < 32);
#pragma unroll
          for (int r = 0; r < 4; r++) {
            const int row = row0 + r;
            float cv = fcos[row * 64 + p];
            float sv = fsin[row * 64 + p];
            float v = acc[mi][ni][r];
            float pv = __shfl_xor(v, 1);
            float o = even ? (v * cv - pv * sv) : (pv * sv + v * cv);
            if (isQ) {
              ((u16*)Cq)[(size_t)row * 4096 + col] = f2bf(o * scale);
            } else {
              Ck[(size_t)row * 1024 + col] = f2bf(o);
            }
          }
        } else {  // V: transposed bf16 store to V^T (ld 2048)
          u32 lo = (u32)f2bf(acc[mi][ni][0]) | ((u32)f2bf(acc[mi][ni][1]) << 16);
          u32 hi = (u32)f2bf(acc[mi][ni][2]) | ((u32)f2bf(acc[mi][ni][3]) << 16);
          uint2 val; val.x = lo; val.y = hi;
          *(uint2*)(&Cv[(size_t)col * 2048 + row0]) = val;
        }
      }
    }
  }
}

// ----------------------------------------------------------- attention ----
// Q (2048,4096) bf16 (RoPE'd, pre-scaled), K (2048,1024) bf16 (RoPE'd),
// Vt (1024,2048) bf16 = V^T. O (2048,4096) bf16.
// grid (S/64, H); 4 waves, wave w owns q rows [q0+16w, q0+16w+16).
// KVBLK=64, double-buffered K/V LDS, 2-phase schedule:
//   STAGE(next buf) -> compute(cur buf) -> vmcnt(0) -> s_barrier (one/tile).
__global__ __launch_bounds__(256) void attn_kernel(const u16* __restrict__ Q,
                                                   const u16* __restrict__ K,
                                                   const u16* __restrict__ Vt,
                                                   u16* __restrict__ O) {
  __shared__ u16 Ks[2][64 * 128];   // [k][d], 256B rows, slot ^= row&7
  __shared__ u16 Vs[2][128 * 64];   // [d][k], 128B rows, slot ^= row&7
  __shared__ u16 Ps[4][16 * 72];    // per-wave P relayout, stride 72

  const int t = threadIdx.x, l = t & 63, w = t >> 6;
  const int li = l & 15, g = l >> 4;
  const int q0 = blockIdx.x * 64;
  const int h = blockIdx.y;
  const int kvh = h >> 2;
  const int qw = q0 + w * 16;

  // Q fragments (held in regs across all kv tiles)
  short8 qf[4];
  {
    const u16* qp = Q + (size_t)(qw + li) * 4096 + h * 128 + g * 8;
#pragma unroll
    for (int kk = 0; kk < 4; kk++) qf[kk] = *(const short8*)(qp + kk * 32);
  }

  // staging: per-wave 4 chunks of 1KB for K tile (16KB) and V tile (16KB)
  const u16* gK[4];
  const u16* gV[4];
  int ldsOff[4];
#pragma unroll
  for (int i = 0; i < 4; i++) {
    int rK = 16 * w + 4 * i + (l >> 4);            // K tile row (256B rows)
    int sK = (l & 15) ^ (rK & 7);
    gK[i] = K + (size_t)rK * 1024 + kvh * 128 + sK * 8;
    int rV = 32 * w + 8 * i + (l >> 3);            // V^T tile row (128B rows)
    int sV = (l & 7) ^ (rV & 7);
    gV[i] = Vt + (size_t)(kvh * 128 + rV) * 2048 + sV * 8;
    ldsOff[i] = (4 * w + i) * 1024;
  }

  int offK[4][4];
#pragma unroll
  for (int n = 0; n < 4; n++) {
    int r = 16 * n + li;
#pragma unroll
    for (int kk = 0; kk < 4; kk++)
      offK[n][kk] = r * 256 + (((kk * 4 + g) ^ (r & 7)) << 4);
  }
  int offV[2][8];
#pragma unroll
  for (int kb = 0; kb < 2; kb++)
#pragma unroll
    for (int dt = 0; dt < 8; dt++) {
      int d = dt * 16 + li;
      offV[kb][dt] = d * 128 + (((kb * 4 + g) ^ (d & 7)) << 4);
    }

  float mrow[4] = {-1e30f, -1e30f, -1e30f, -1e30f};
  float lsum[4] = {0.f, 0.f, 0.f, 0.f};
  floatx4 accO[8] = {};

  int klo = q0 - 1023;
  if (klo < 0) klo = 0;
  klo &= ~63;
  const int nt = (q0 + 64 - klo) >> 6;

  auto stage = [&](int buf, int k0) {
    char* ksb = (char*)&Ks[buf][0];
    char* vsb = (char*)&Vs[buf][0];
#pragma unroll
    for (int i = 0; i < 4; i++) GLDS16(gK[i] + (size_t)k0 * 1024, ksb + ldsOff[i]);
#pragma unroll
    for (int i = 0; i < 4; i++) GLDS16(gV[i] + k0, vsb + ldsOff[i]);
  };

  stage(0, klo);
  asm volatile("s_waitcnt vmcnt(0)" ::: "memory");
  __builtin_amdgcn_s_barrier();

  for (int it = 0; it < nt; it++) {
    const int k0 = klo + (it << 6);
    if (it + 1 < nt) stage((it + 1) & 1, k0 + 64);

    if (k0 <= qw + 15 && k0 + 63 >= qw - 1023) {
      const char* kb = (const char*)&Ks[it & 1][0];
      const char* vb = (const char*)&Vs[it & 1][0];
      floatx4 s[4] = {};
      __builtin_amdgcn_s_setprio(1);
#pragma unroll
      for (int kk = 0; kk < 4; kk++)
#pragma unroll
        for (int n = 0; n < 4; n++) {
          short8 kf = *(const short8*)(kb + offK[n][kk]);
          s[n] = __builtin_amdgcn_mfma_f32_16x16x32_bf16(qf[kk], kf, s[n], 0, 0, 0);
        }
      __builtin_amdgcn_s_setprio(0);
      // windowed causal mask
      const bool full = (k0 + 63 <= qw) && (k0 >= qw + 15 - 1023);
      if (!full) {
#pragma unroll
        for (int n = 0; n < 4; n++) {
          const int kc = k0 + n * 16 + li;
#pragma unroll
          for (int r = 0; r < 4; r++) {
            const int qr = qw + 4 * g + r;
            if (kc > qr || qr - kc > 1023) s[n][r] = -__builtin_inff();
          }
        }
      }
      // row max (over 4 n-tiles in-lane, then 16 lanes)
      float rm[4];
#pragma unroll
      for (int r = 0; r < 4; r++)
        rm[r] = fmaxf(fmaxf(s[0][r], s[1][r]), fmaxf(s[2][r], s[3][r]));
#pragma unroll
      for (int msk = 1; msk <= 8; msk <<= 1)
#pragma unroll
        for (int r = 0; r < 4; r++) rm[r] = fmaxf(rm[r], __shfl_xor(rm[r], msk));
      // online-softmax update
      float al[4];
#pragma unroll
      for (int r = 0; r < 4; r++) {
        float mn = fmaxf(mrow[r], rm[r]);
        al[r] = __expf(mrow[r] - mn);
        mrow[r] = mn;
        lsum[r] *= al[r];
      }
#pragma unroll
      for (int dt = 0; dt < 8; dt++)
#pragma unroll
        for (int r = 0; r < 4; r++) accO[dt][r] *= al[r];
      // P = exp(S - m), row sums, relayout via per-wave LDS
      float rs[4] = {0.f, 0.f, 0.f, 0.f};
      u16* pw = &Ps[w][0];
#pragma unroll
      for (int n = 0; n < 4; n++)
#pragma unroll
        for (int r = 0; r < 4; r++) {
          float p = __expf(s[n][r] - mrow[r]);
          rs[r] += p;
          pw[(4 * g + r) * 72 + n * 16 + li] = f2bf(p);
        }
#pragma unroll
      for (int msk = 1; msk <= 8; msk <<= 1)
#pragma unroll
        for (int r = 0; r < 4; r++) rs[r] += __shfl_xor(rs[r], msk);
#pragma unroll
      for (int r = 0; r < 4; r++) lsum[r] += rs[r];
      short8 pa[2];
#pragma unroll
      for (int kbi = 0; kbi < 2; kbi++)
        pa[kbi] = *(const short8*)((const char*)&Ps[w][0] + li * 144 + kbi * 64 + g * 16);
      // PV
      __builtin_amdgcn_s_setprio(1);
#pragma unroll
      for (int kbi = 0; kbi < 2; kbi++)
#pragma unroll
        for (int dt = 0; dt < 8; dt++) {
          short8 vf = *(const short8*)(vb + offV[kbi][dt]);
          accO[dt] = __builtin_amdgcn_mfma_f32_16x16x32_bf16(pa[kbi], vf, accO[dt], 0, 0, 0);
        }
      __builtin_amdgcn_s_setprio(0);
    }
    asm volatile("s_waitcnt vmcnt(0)" ::: "memory");
    __builtin_amdgcn_s_barrier();
  }

  float inv[4];
#pragma unroll
  for (int r = 0; r < 4; r++) inv[r] = 1.0f / lsum[r];
#pragma unroll
  for (int dt = 0; dt < 8; dt++)
#pragma unroll
    for (int r = 0; r < 4; r++)
      O[(size_t)(qw + 4 * g + r) * 4096 + h * 128 + dt * 16 + li] =
          f2bf(accO[dt][r] * inv[r]);
}

// -------------------------------------------------------------- launch ----
extern "C" void kernel_launch(void* const* d_in, const int* in_sizes, int n_in,
                              void* d_out, int out_size, void* d_ws, size_t ws_size,
                              hipStream_t stream) {
  const float* x    = (const float*)d_in[0];
  const float* wq   = (const float*)d_in[1];
  const float* wk   = (const float*)d_in[2];
  const float* wv   = (const float*)d_in[3];
  const float* wo   = (const float*)d_in[4];
  const float* fcos = (const float*)d_in[5];
  const float* fsin = (const float*)d_in[6];
  // d_in[7] mask, d_in[8] positions: unused (window implemented analytically)

  u16* ws  = (u16*)d_ws;
  u16* xb  = ws;               // 2048x4096
  u16* wqb = xb + 8388608;     // 4096x4096
  u16* wkb = wqb + 16777216;   // 1024x4096
  u16* wvb = wkb + 4194304;    // 1024x4096
  u16* wob = wvb + 4194304;    // 4096x4096
  u16* Qb  = wob + 16777216;   // 2048x4096
  u16* Kb  = Qb + 8388608;     // 2048x1024
  u16* Vtb = Kb + 2097152;     // 1024x2048 (V^T)
  u16* AOb = Vtb + 2097152;    // 2048x4096

  cast_all<<<2048, 256, 0, stream>>>(x, wq, wk, wv, wo, xb, wqb, wkb, wvb, wob);
  gemm_pipe<1><<<dim3(48, 16), 256, 0, stream>>>(xb, wqb, wkb, wvb, Qb, Kb, Vtb, fcos, fsin);
  attn_kernel<<<dim3(32, 32), 256, 0, stream>>>(Qb, Kb, Vtb, AOb);
  gemm_pipe<0><<<dim3(32, 16), 256, 0, stream>>>(AOb, wob, nullptr, nullptr, d_out, nullptr, nullptr, nullptr, nullptr);
}